// Round 1
// baseline (26.779 us; speedup 1.0000x reference)
//
#include <hip/hip_runtime.h>
#include <hip/hip_bf16.h>

// Stage 1+2: build zero-padded intermediate image inp_p[64][30][30] (fp32).
// inp_p[c][y][x] = inp[c][y-1][x-1] for interior, 0 on the 1-wide border.
// inp[c=2l+k][m][n] = sum_{jj in 0..1} sum_{i in 0..2} x[2l+jj][m][n+i-1] * w2[2l+jj][i][k]
__global__ void prep_kernel(const float* __restrict__ x,
                            const float* __restrict__ w2,
                            float* __restrict__ inp) {
    int idx = blockIdx.x * 256 + threadIdx.x;     // 0 .. 57599
    if (idx >= 64 * 30 * 30) return;
    int c   = idx / 900;
    int rem = idx % 900;
    int yp  = rem / 30;
    int xq  = rem % 30;
    float v = 0.f;
    if (yp >= 1 && yp <= 28 && xq >= 1 && xq <= 28) {
        int m = yp - 1, n = xq - 1;
        int l = c >> 1, k = c & 1;
        float acc = 0.f;
        for (int jj = 0; jj < 2; ++jj) {
            int j = l * 2 + jj;
            const float* xrow = x + (j * 28 + m) * 28;
            const float* w2p  = w2 + (j * 3) * 2 + k;   // w2[j][i][k], i stride 2
            for (int i = 0; i < 3; ++i) {
                int nn = n + i - 1;
                float xv = (nn >= 0 && nn < 28) ? xrow[nn] : 0.f;
                acc += xv * w2p[i * 2];
            }
        }
        v = acc;
    }
    inp[idx] = v;
}

// Stage 3: 3x3 conv, pad 1, Cin=64, Cout=128, 28x28 spatial.
// One wave per block; o is wave-uniform -> weight loads become scalar loads.
// Lane covers output (row R = hg*4 + dh, cols w0, w0+1), 56 active lanes.
__global__ __launch_bounds__(64) void conv_kernel(const float* __restrict__ inp,
                                                  const float* __restrict__ w1,
                                                  float* __restrict__ y) {
    int b    = blockIdx.x;        // 0..895
    int o    = b / 7;             // wave-uniform output channel
    int hg   = b % 7;             // rows hg*4 .. hg*4+3
    int lane = threadIdx.x;       // 0..63
    int dh   = lane / 14;
    int wp   = lane % 14;
    bool active = (lane < 56);
    if (!active) { dh = 0; wp = 0; }   // keep reads in bounds for idle lanes
    int R  = hg * 4 + dh;         // output row
    int w0 = wp * 2;              // output cols w0, w0+1

    float acc0 = 0.f, acc1 = 0.f;
    const float* wbase = w1 + o * (32 * 3 * 3 * 2);   // w1[o][l][r][s][k]

    for (int c = 0; c < 64; ++c) {
        int l = c >> 1, k = c & 1;
        const float* w9 = wbase + l * 18 + k;         // element (r,s) at +(r*3+s)*2
        float w00 = w9[0],  w01 = w9[2],  w02 = w9[4];
        float w10 = w9[6],  w11 = w9[8],  w12 = w9[10];
        float w20 = w9[12], w21 = w9[14], w22 = w9[16];

        const float* ip = inp + c * 900 + R * 30 + w0;  // padded (R+dy, w0+dx)
        float2 a0 = *(const float2*)(ip + 0);
        float2 a1 = *(const float2*)(ip + 2);
        float2 b0 = *(const float2*)(ip + 30);
        float2 b1 = *(const float2*)(ip + 32);
        float2 c0 = *(const float2*)(ip + 60);
        float2 c1 = *(const float2*)(ip + 62);

        acc0 += a0.x * w00 + a0.y * w01 + a1.x * w02
              + b0.x * w10 + b0.y * w11 + b1.x * w12
              + c0.x * w20 + c0.y * w21 + c1.x * w22;
        acc1 += a0.y * w00 + a1.x * w01 + a1.y * w02
              + b0.y * w10 + b1.x * w11 + b1.y * w12
              + c0.y * w20 + c1.x * w21 + c1.y * w22;
    }

    if (active) {
        float* yp = y + (o * 28 + R) * 28 + w0;
        yp[0] = acc0;
        yp[1] = acc1;
    }
}

extern "C" void kernel_launch(void* const* d_in, const int* in_sizes, int n_in,
                              void* d_out, int out_size, void* d_ws, size_t ws_size,
                              hipStream_t stream) {
    const float* x  = (const float*)d_in[0];   // (1,64,28,28) fp32
    const float* w1 = (const float*)d_in[1];   // (128,32,3,3,2) fp32
    const float* w2 = (const float*)d_in[2];   // (64,3,2) fp32
    float* yout = (float*)d_out;               // (1,128,28,28) fp32
    float* inp  = (float*)d_ws;                // padded [64][30][30] fp32 = 230400 B

    prep_kernel<<<dim3(225), dim3(256), 0, stream>>>(x, w2, inp);
    conv_kernel<<<dim3(896), dim3(64), 0, stream>>>(inp, w1, yout);
}